// Round 10
// baseline (446.118 us; speedup 1.0000x reference)
//
#include <hip/hip_runtime.h>
#include <math.h>

#define NF 128

typedef __attribute__((ext_vector_type(8))) short short8;
typedef __attribute__((ext_vector_type(4))) float floatx4;

__device__ __forceinline__ unsigned short f2bf(float f) {
    union { float x; unsigned int i; } c; c.x = f;
    unsigned int r = c.i + 0x7fffu + ((c.i >> 16) & 1u);   // RNE
    return (unsigned short)(r >> 16);
}
__device__ __forceinline__ float bf2f(unsigned short u) {
    union { unsigned int i; float x; } c; c.i = ((unsigned int)u) << 16;
    return c.x;
}
__device__ __forceinline__ void unpack8(uint4 u, float* f) {
    union { unsigned int i; float x; } c;
    c.i = u.x << 16;          f[0] = c.x;
    c.i = u.x & 0xffff0000u;  f[1] = c.x;
    c.i = u.y << 16;          f[2] = c.x;
    c.i = u.y & 0xffff0000u;  f[3] = c.x;
    c.i = u.z << 16;          f[4] = c.x;
    c.i = u.z & 0xffff0000u;  f[5] = c.x;
    c.i = u.w << 16;          f[6] = c.x;
    c.i = u.w & 0xffff0000u;  f[7] = c.x;
}
__device__ __forceinline__ ushort4 pack4(float a, float b, float c, float d) {
    ushort4 h; h.x = f2bf(a); h.y = f2bf(b); h.z = f2bf(c); h.w = f2bf(d);
    return h;
}

// ======= merged: fp32->bf16 weight convert (blocks 0..319) ∥ hist (rest) ====
__global__ __launch_bounds__(256) void wconv_hist_kernel(
    const float* __restrict__ a, const float* __restrict__ b,
    const float* __restrict__ c, const float* __restrict__ d,
    const float* __restrict__ e, unsigned short* __restrict__ o,
    const int* __restrict__ eid, int* __restrict__ cnt,
    int* __restrict__ rank, int E)
{
    int blk = blockIdx.x;
    if (blk < 320) {
        int i = blk * 256 + threadIdx.x;       // 5*16384 total
        int w = i >> 14, j = i & 16383;
        const float* p = (w == 0) ? a : (w == 1) ? b : (w == 2) ? c : (w == 3) ? d : e;
        o[i] = f2bf(p[j]);
    } else {
        int i = (blk - 320) * 256 + threadIdx.x;
        if (i < E) rank[i] = atomicAdd(&cnt[eid[i]], 1);
    }
}

__global__ __launch_bounds__(256) void scan1_kernel(
    const int* __restrict__ cnt, int* __restrict__ bsum, int n)
{
    int base = blockIdx.x * 1024;
    int s = 0;
    #pragma unroll
    for (int p = 0; p < 4; ++p) {
        int i = base + (int)threadIdx.x + p * 256;
        if (i < n) s += cnt[i];
    }
    #pragma unroll
    for (int m = 1; m <= 32; m <<= 1) s += __shfl_xor(s, m, 64);
    __shared__ int ws_[4];
    int wid = threadIdx.x >> 6;
    if ((threadIdx.x & 63) == 0) ws_[wid] = s;
    __syncthreads();
    if (threadIdx.x == 0) bsum[blockIdx.x] = ws_[0] + ws_[1] + ws_[2] + ws_[3];
}

// ======= merged: scan3 (blocks 0..nb-1) ∥ LN+GELU (rest) ===================
__global__ __launch_bounds__(256) void scan3_ln_kernel(
    const int* __restrict__ cnt, const int* __restrict__ bsum,
    int* __restrict__ row_start, int n, int nb,
    const float* __restrict__ in_feats, const float* __restrict__ gamma,
    const float* __restrict__ beta, unsigned short* __restrict__ deltab, int M)
{
    int blk = blockIdx.x;
    if (blk < nb) {
        __shared__ int base_off;
        int tid = threadIdx.x, lane = tid & 63, wid = tid >> 6;
        if (tid == 0) {
            int a = 0;
            for (int j = 0; j < blk; ++j) a += bsum[j];
            base_off = a;
            if (blk == nb - 1) {
                int tot = a;
                for (int j = blk; j < nb; ++j) tot += bsum[j];
                row_start[n] = tot;
            }
        }
        int base = blk * 1024;
        int v[4]; int s = 0;
        #pragma unroll
        for (int p = 0; p < 4; ++p) {
            int i = base + tid * 4 + p;
            v[p] = (i < n) ? cnt[i] : 0;
            s += v[p];
        }
        int ss = s;
        #pragma unroll
        for (int off = 1; off < 64; off <<= 1) {
            int t = __shfl_up(ss, off, 64);
            if (lane >= off) ss += t;
        }
        __shared__ int wsum[4];
        if (lane == 63) wsum[wid] = ss;
        __syncthreads();
        int woff = 0;
        for (int j = 0; j < wid; ++j) woff += wsum[j];
        int a = base_off + woff + (ss - s);
        #pragma unroll
        for (int p = 0; p < 4; ++p) {
            int i = base + tid * 4 + p;
            if (i < n) { row_start[i] = a; a += v[p]; }
        }
        return;
    }
    // ---- LN + GELU (4 threads/row) ----
    int li = (blk - nb) * 256 + threadIdx.x;
    int row = li >> 2, t4 = li & 3;
    if (row >= M) return;
    size_t rbase = (size_t)row * NF;

    const float4* ip = (const float4*)(in_feats + rbase) + t4 * 8;
    float4 xf[8];
    #pragma unroll
    for (int p = 0; p < 8; ++p) xf[p] = ip[p];
    float s = 0.f, sq = 0.f;
    #pragma unroll
    for (int p = 0; p < 8; ++p) {
        s  += xf[p].x + xf[p].y + xf[p].z + xf[p].w;
        sq += xf[p].x * xf[p].x + xf[p].y * xf[p].y
            + xf[p].z * xf[p].z + xf[p].w * xf[p].w;
    }
    s  += __shfl_xor(s, 1, 64);  s  += __shfl_xor(s, 2, 64);
    sq += __shfl_xor(sq, 1, 64); sq += __shfl_xor(sq, 2, 64);
    float mu = s * (1.0f / 128.0f);
    float var = sq * (1.0f / 128.0f) - mu * mu;
    float rstd = rsqrtf(var + 1e-5f);

    const float4* gp = (const float4*)gamma + t4 * 8;
    const float4* bp = (const float4*)beta + t4 * 8;
    uint dreg[16];
    #pragma unroll
    for (int p = 0; p < 8; ++p) {
        float4 g4 = gp[p], b4 = bp[p];
        float o0 = (xf[p].x - mu) * rstd * g4.x + b4.x;
        float o1 = (xf[p].y - mu) * rstd * g4.y + b4.y;
        float o2 = (xf[p].z - mu) * rstd * g4.z + b4.z;
        float o3 = (xf[p].w - mu) * rstd * g4.w + b4.w;
        o0 = 0.5f * o0 * (1.0f + erff(o0 * 0.70710678118654752f));
        o1 = 0.5f * o1 * (1.0f + erff(o1 * 0.70710678118654752f));
        o2 = 0.5f * o2 * (1.0f + erff(o2 * 0.70710678118654752f));
        o3 = 0.5f * o3 * (1.0f + erff(o3 * 0.70710678118654752f));
        ushort4 h = pack4(o0, o1, o2, o3);
        dreg[p * 2]     = (uint)h.x | ((uint)h.y << 16);
        dreg[p * 2 + 1] = (uint)h.z | ((uint)h.w << 16);
    }
    uint4* od = (uint4*)(deltab + rbase + t4 * 32);
    #pragma unroll
    for (int q = 0; q < 4; ++q)
        od[q] = make_uint4(dreg[q*4], dreg[q*4+1], dreg[q*4+2], dreg[q*4+3]);
}

// ======= merged: scatter (blocks 0..sb-1) ∥ gemm_dv (rest) — round-8 proven =
__global__ __launch_bounds__(256) void scatter_dv_kernel(
    const int* __restrict__ eid, const float* __restrict__ ew,
    const int* __restrict__ row_start, const int* __restrict__ rank,
    int2* __restrict__ edata, int E, int sb,
    const float* __restrict__ struc, const unsigned short* __restrict__ deltab,
    const unsigned short* __restrict__ Wall, const float* __restrict__ bs,
    const float* __restrict__ bv, unsigned short* __restrict__ dstrb,
    unsigned short* __restrict__ kvb, int M, int nt, int ndv)
{
    __shared__ unsigned short Wl[128][136];
    __shared__ unsigned short Cst[64][136];

    int blk = blockIdx.x;
    if (blk < sb) {    // ---- scatter role (no LDS use) ----
        int i = blk * 256 + threadIdx.x;
        if (i < E) {
            int src = eid[i];
            int pos = row_start[src] + rank[i];
            edata[pos] = make_int2(eid[E + i], __float_as_int(ew[i]));
        }
        return;
    }

    // ---- gemm_dv role ----
    int idx = blk - sb;            // 0..2*ndv-1
    int y = idx / ndv;             // 0=dstr 1=v
    int xb = idx % ndv;

    int tid = threadIdx.x;
    int lane = tid & 63, w = tid >> 6, lg = lane & 15, quad = lane >> 4;

    const unsigned short* Wg = Wall + ((y == 0) ? 0 : 3 * 16384);  // Ws or Wv
    const float* bias = (y == 0) ? bs : bv;
    unsigned short* outg = (y == 0) ? dstrb : (kvb + NF);
    int ostride = (y == 0) ? NF : 2 * NF;

    {
        const uint4* g = (const uint4*)Wg;
        #pragma unroll
        for (int p = 0; p < 8; ++p) {
            int i2 = tid + p * 256;
            *(uint4*)&Wl[i2 >> 4][(i2 & 15) * 8] = g[i2];
        }
    }
    float br[8];
    #pragma unroll
    for (int t = 0; t < 8; ++t) br[t] = bias[t * 16 + lg];
    __syncthreads();   // the only barrier

    for (int tile = xb; tile < nt; tile += ndv) {
        int m0 = tile * 64;
        int am = m0 + w * 16 + lg;
        size_t rb = (size_t)(am < M ? am : 0) * NF;

        short8 af[4];
        if (y == 0) {   // struc fp32 -> bf16 A-frags
            const float4* sp = (const float4*)(struc + rb);
            #pragma unroll
            for (int ks = 0; ks < 4; ++ks) {
                float4 f0 = sp[ks * 8 + quad * 2];
                float4 f1 = sp[ks * 8 + quad * 2 + 1];
                ushort4 h0 = pack4(f0.x, f0.y, f0.z, f0.w);
                ushort4 h1 = pack4(f1.x, f1.y, f1.z, f1.w);
                uint4 pk = make_uint4((uint)h0.x | ((uint)h0.y << 16),
                                      (uint)h0.z | ((uint)h0.w << 16),
                                      (uint)h1.x | ((uint)h1.y << 16),
                                      (uint)h1.z | ((uint)h1.w << 16));
                af[ks] = *(short8*)&pk;
            }
        } else {
            const unsigned short* arow = deltab + rb + quad * 8;
            #pragma unroll
            for (int ks = 0; ks < 4; ++ks) af[ks] = *(const short8*)(arow + ks * 32);
        }

        floatx4 acc[8];
        #pragma unroll
        for (int t = 0; t < 8; ++t) acc[t] = (floatx4){0.f, 0.f, 0.f, 0.f};
        #pragma unroll
        for (int ks = 0; ks < 4; ++ks) {
            #pragma unroll
            for (int t = 0; t < 8; ++t) {
                short8 b = *(const short8*)&Wl[t * 16 + lg][ks * 32 + quad * 8];
                acc[t] = __builtin_amdgcn_mfma_f32_16x16x32_bf16(af[ks], b, acc[t], 0, 0, 0);
            }
        }

        // epilogue
        if (y == 0) {
            #pragma unroll
            for (int t = 0; t < 8; ++t) {
                int col = t * 16 + lg;
                #pragma unroll
                for (int r = 0; r < 4; ++r) {
                    int gm = m0 + w * 16 + quad * 4 + r;
                    float dadd = bf2f(deltab[(size_t)(gm < M ? gm : 0) * NF + col]);
                    Cst[w * 16 + quad * 4 + r][col] = f2bf(acc[t][r] + br[t] + dadd);
                }
            }
        } else {
            #pragma unroll
            for (int t = 0; t < 8; ++t) {
                int col = t * 16 + lg;
                #pragma unroll
                for (int r = 0; r < 4; ++r)
                    Cst[w * 16 + quad * 4 + r][col] = f2bf(acc[t][r] + br[t]);
            }
        }
        #pragma unroll
        for (int p = 0; p < 4; ++p) {
            int i2 = lane + p * 64;
            int row = w * 16 + (i2 >> 4), c16 = i2 & 15;
            int gm = m0 + row;
            if (gm < M)
                *(uint4*)(outg + (size_t)gm * ostride + c16 * 8) = *(const uint4*)&Cst[row][c16 * 8];
        }
    }
}

// ========== gemm_qk (round-8 proven: LDS W, grid-stride) ==================
__global__ __launch_bounds__(256) void gemm_qk_kernel(
    const unsigned short* __restrict__ dstrb, const unsigned short* __restrict__ Wall,
    const float* __restrict__ bq, const float* __restrict__ bk,
    unsigned short* __restrict__ qb, unsigned short* __restrict__ kvb,
    int M, int nt)
{
    __shared__ unsigned short Wl[128][136];
    __shared__ unsigned short Cst[64][136];

    int tid = threadIdx.x;
    int y = blockIdx.y;                       // 0=q 1=k
    int lane = tid & 63, w = tid >> 6, lg = lane & 15, quad = lane >> 4;

    const unsigned short* Wg = Wall + (y + 1) * 16384;   // Wq or Wk
    const float* bias = (y == 0) ? bq : bk;
    float scale = (y == 0) ? 0.25f : 1.0f;
    unsigned short* outg = (y == 0) ? qb : kvb;
    int ostride = (y == 0) ? NF : 2 * NF;

    {
        const uint4* g = (const uint4*)Wg;
        #pragma unroll
        for (int p = 0; p < 8; ++p) {
            int idx = tid + p * 256;
            *(uint4*)&Wl[idx >> 4][(idx & 15) * 8] = g[idx];
        }
    }
    float br[8];
    #pragma unroll
    for (int t = 0; t < 8; ++t) br[t] = bias[t * 16 + lg] * scale;
    __syncthreads();   // the only barrier

    for (int tile = blockIdx.x; tile < nt; tile += gridDim.x) {
        int m0 = tile * 64;
        int am = m0 + w * 16 + lg;
        const unsigned short* arow = dstrb + (size_t)(am < M ? am : 0) * NF + quad * 8;

        floatx4 acc[8];
        #pragma unroll
        for (int t = 0; t < 8; ++t) acc[t] = (floatx4){0.f, 0.f, 0.f, 0.f};
        short8 af[4];
        #pragma unroll
        for (int ks = 0; ks < 4; ++ks) af[ks] = *(const short8*)(arow + ks * 32);
        #pragma unroll
        for (int ks = 0; ks < 4; ++ks) {
            #pragma unroll
            for (int t = 0; t < 8; ++t) {
                short8 b = *(const short8*)&Wl[t * 16 + lg][ks * 32 + quad * 8];
                acc[t] = __builtin_amdgcn_mfma_f32_16x16x32_bf16(af[ks], b, acc[t], 0, 0, 0);
            }
        }
        #pragma unroll
        for (int t = 0; t < 8; ++t) {
            int col = t * 16 + lg;
            #pragma unroll
            for (int r = 0; r < 4; ++r)
                Cst[w * 16 + quad * 4 + r][col] = f2bf(acc[t][r] * scale + br[t]);
        }
        #pragma unroll
        for (int p = 0; p < 4; ++p) {
            int idx = lane + p * 64;
            int row = w * 16 + (idx >> 4), c16 = idx & 15;
            int gm = m0 + row;
            if (gm < M)
                *(uint4*)(outg + (size_t)gm * ostride + c16 * 8) = *(const uint4*)&Cst[row][c16 * 8];
        }
    }
}

// ---------------- aggregation + fused out-projection ----------------
// 4 nodes/block (1 wave each); gather loop unchanged (proven). Epilogue:
// every lane holds the full agg row after the xor-butterfly; pack to bf16
// A-frags via shfl and MFMA against Wo (B from global, issued once per wave,
// hidden under other blocks' gather latency). Lanes 0-15 hold C row 0 =
// the out row; add in_feats, store fp32. No barriers, no agg round-trip.
__global__ __launch_bounds__(256) void aggregate_out_kernel(
    const unsigned short* __restrict__ Q, const unsigned short* __restrict__ kvb,
    const int* __restrict__ row_start, const int2* __restrict__ edata,
    const unsigned short* __restrict__ Wo4, const float* __restrict__ in_feats,
    float* __restrict__ out, int N)
{
    int node = blockIdx.x * 4 + (threadIdx.x >> 6);
    if (node >= N) return;
    int lane = threadIdx.x & 63;
    int sg = lane >> 4, lg = lane & 15;
    int rs = row_start[node], re = row_start[node + 1];

    float qv[8];
    unpack8(*(const uint4*)(Q + (size_t)node * NF + lg * 8), qv);
    float acc[8];
    #pragma unroll
    for (int j = 0; j < 8; ++j) acc[j] = 0.f;

    int e1 = rs + sg, e2 = rs + sg + 4;
    int2 ed1 = (e1 < re) ? edata[e1] : make_int2(0, 0);
    int2 ed2 = (e2 < re) ? edata[e2] : make_int2(0, 0);

    for (int e0 = rs; e0 < re; e0 += 8) {
        int2 c1 = ed1, c2 = ed2;
        int en1 = e0 + 8 + sg, en2 = en1 + 4;
        ed1 = (en1 < re) ? edata[en1] : make_int2(0, 0);
        ed2 = (en2 < re) ? edata[en2] : make_int2(0, 0);

        // issue all 4 gathers up front (K,V adjacent lines per edge)
        const uint4* p1 = (const uint4*)kvb + (size_t)c1.x * 32 + lg;
        const uint4* p2 = (const uint4*)kvb + (size_t)c2.x * 32 + lg;
        uint4 k1u = p1[0], v1u = p1[16];
        uint4 k2u = p2[0], v2u = p2[16];

        float kv1[8], kv2[8];
        unpack8(k1u, kv1);
        unpack8(k2u, kv2);
        float s1 = qv[0] * kv1[0], s2 = qv[0] * kv2[0];
        #pragma unroll
        for (int j = 1; j < 8; ++j) {
            s1 = fmaf(qv[j], kv1[j], s1);
            s2 = fmaf(qv[j], kv2[j], s2);
        }
        s1 += __shfl_xor(s1, 1, 64);    // head = 16 feats = 2 adjacent lanes
        s2 += __shfl_xor(s2, 1, 64);
        float a1 = __int_as_float(c1.y) / (1.f + __expf(-s1));
        float a2 = __int_as_float(c2.y) / (1.f + __expf(-s2));

        float vv1[8], vv2[8];
        unpack8(v1u, vv1);
        unpack8(v2u, vv2);
        #pragma unroll
        for (int j = 0; j < 8; ++j) {
            acc[j] = fmaf(a1, vv1[j], acc[j]);
            acc[j] = fmaf(a2, vv2[j], acc[j]);
        }
    }
    #pragma unroll
    for (int j = 0; j < 8; ++j) {
        acc[j] += __shfl_xor(acc[j], 16, 64);
        acc[j] += __shfl_xor(acc[j], 32, 64);
    }
    // every lane now holds the complete agg row (cols (lane&15)*8 .. +8).

    // ---- fused out-proj: out = in_feats + agg @ Wo^T (per-wave MFMA) ----
    floatx4 po[8];
    #pragma unroll
    for (int t = 0; t < 8; ++t) po[t] = (floatx4){0.f, 0.f, 0.f, 0.f};
    #pragma unroll
    for (int ks = 0; ks < 4; ++ks) {
        // lane needs agg[k], k = ks*32 + sg*8 + j -> source lane ks*4+sg
        float f0 = __shfl(acc[0], ks * 4 + sg, 64);
        float f1 = __shfl(acc[1], ks * 4 + sg, 64);
        float f2 = __shfl(acc[2], ks * 4 + sg, 64);
        float f3 = __shfl(acc[3], ks * 4 + sg, 64);
        float f4 = __shfl(acc[4], ks * 4 + sg, 64);
        float f5 = __shfl(acc[5], ks * 4 + sg, 64);
        float f6 = __shfl(acc[6], ks * 4 + sg, 64);
        float f7 = __shfl(acc[7], ks * 4 + sg, 64);
        uint4 pk = make_uint4((uint)f2bf(f0) | ((uint)f2bf(f1) << 16),
                              (uint)f2bf(f2) | ((uint)f2bf(f3) << 16),
                              (uint)f2bf(f4) | ((uint)f2bf(f5) << 16),
                              (uint)f2bf(f6) | ((uint)f2bf(f7) << 16));
        short8 a = *(short8*)&pk;
        #pragma unroll
        for (int t = 0; t < 8; ++t) {
            short8 b = *(const short8*)(Wo4 + ((t * 16 + lg) << 7) + ks * 32 + sg * 8);
            po[t] = __builtin_amdgcn_mfma_f32_16x16x32_bf16(a, b, po[t], 0, 0, 0);
        }
    }
    if (sg == 0) {   // lanes 0-15: C row 0 lives in reg 0
        size_t ob = (size_t)node * NF;
        #pragma unroll
        for (int t = 0; t < 8; ++t) {
            int c = t * 16 + lg;
            out[ob + c] = po[t][0] + in_feats[ob + c];
        }
    }
}

extern "C" void kernel_launch(void* const* d_in, const int* in_sizes, int n_in,
                              void* d_out, int out_size, void* d_ws, size_t ws_size,
                              hipStream_t stream)
{
    const float* in_feats = (const float*)d_in[0];
    const float* struc    = (const float*)d_in[1];
    const float* eweights = (const float*)d_in[2];
    const float* ln_scale = (const float*)d_in[3];
    const float* ln_bias  = (const float*)d_in[4];
    const float* Ws       = (const float*)d_in[5];
    const float* bs       = (const float*)d_in[6];
    const float* Wq       = (const float*)d_in[7];
    const float* bq       = (const float*)d_in[8];
    const float* Wk       = (const float*)d_in[9];
    const float* bk       = (const float*)d_in[10];
    const float* Wv       = (const float*)d_in[11];
    const float* bv       = (const float*)d_in[12];
    const float* Wo       = (const float*)d_in[13];
    const int*   edge_ids = (const int*)d_in[14];
    float* out = (float*)d_out;

    int N = in_sizes[0] / NF;   // 50000
    int E = in_sizes[2];        // 800000

    // ---- workspace
    size_t F = (size_t)N * NF;
    unsigned short* deltab = (unsigned short*)d_ws;
    unsigned short* dstrb  = deltab + F;
    unsigned short* qb     = dstrb + F;
    unsigned short* kvb    = qb + F;            // 2F: [K|V] interleaved per node
    unsigned short* Wall   = kvb + 2 * F;       // 5*16384: Ws,Wq,Wk,Wv,Wo
    int2*  edata     = (int2*)(Wall + 5 * 16384);
    int*   cnt       = (int*)(edata + E);
    int*   row_start = cnt + N;                 // N+1
    int*   bsum      = row_start + N + 1;       // 64
    int*   rank      = bsum + 64;               // E

    int nt  = (N + 63) / 64;    // 782 row-tiles
    int geb = (E + 255) / 256;  // 3125 edge blocks
    int nb  = (N + 1023) / 1024;
    int ppb = (N * 4 + 255) / 256;  // 782 LN blocks
    int ndv = 261;                  // dv blocks per y-slice

    // cnt -> 0, then weights-convert ∥ histogram (one dispatch)
    hipMemsetAsync(cnt, 0, (size_t)N * sizeof(int), stream);
    wconv_hist_kernel<<<320 + geb, 256, 0, stream>>>(Ws, Wq, Wk, Wv, Wo, Wall,
                                                     edge_ids, cnt, rank, E);

    scan1_kernel<<<nb, 256, 0, stream>>>(cnt, bsum, N);

    // scan3 ∥ LN+GELU (one dispatch; independent work)
    scan3_ln_kernel<<<nb + ppb, 256, 0, stream>>>(cnt, bsum, row_start, N, nb,
                                                  in_feats, ln_scale, ln_bias,
                                                  deltab, N);

    // scatter ∥ gemm_dv (one dispatch; scatter writeback drains under MFMA)
    scatter_dv_kernel<<<geb + 2 * ndv, 256, 0, stream>>>(edge_ids, eweights,
                                                         row_start, rank, edata, E, geb,
                                                         struc, deltab, Wall, bs, bv,
                                                         dstrb, kvb, N, nt, ndv);

    gemm_qk_kernel<<<dim3(261, 2), 256, 0, stream>>>(dstrb, Wall, bq, bk,
                                                     qb, kvb, N, nt);

    // edge attention + segment-sum + fused out-projection
    aggregate_out_kernel<<<(N + 3) / 4, 256, 0, stream>>>(qb, kvb, row_start, edata,
                                                          Wall + 4 * 16384,
                                                          in_feats, out, N);
}

// Round 11
// 299.942 us; speedup vs baseline: 1.4873x; 1.4873x over previous
//
#include <hip/hip_runtime.h>
#include <math.h>

#define NF 128

typedef __attribute__((ext_vector_type(8))) short short8;
typedef __attribute__((ext_vector_type(4))) float floatx4;

__device__ __forceinline__ unsigned short f2bf(float f) {
    union { float x; unsigned int i; } c; c.x = f;
    unsigned int r = c.i + 0x7fffu + ((c.i >> 16) & 1u);   // RNE
    return (unsigned short)(r >> 16);
}
__device__ __forceinline__ float bf2f(unsigned short u) {
    union { unsigned int i; float x; } c; c.i = ((unsigned int)u) << 16;
    return c.x;
}
__device__ __forceinline__ void unpack8(uint4 u, float* f) {
    union { unsigned int i; float x; } c;
    c.i = u.x << 16;          f[0] = c.x;
    c.i = u.x & 0xffff0000u;  f[1] = c.x;
    c.i = u.y << 16;          f[2] = c.x;
    c.i = u.y & 0xffff0000u;  f[3] = c.x;
    c.i = u.z << 16;          f[4] = c.x;
    c.i = u.z & 0xffff0000u;  f[5] = c.x;
    c.i = u.w << 16;          f[6] = c.x;
    c.i = u.w & 0xffff0000u;  f[7] = c.x;
}
__device__ __forceinline__ ushort4 pack4(float a, float b, float c, float d) {
    ushort4 h; h.x = f2bf(a); h.y = f2bf(b); h.z = f2bf(c); h.w = f2bf(d);
    return h;
}

// ======= merged: fp32->bf16 weight convert (blocks 0..319) ∥ hist (rest) ====
__global__ __launch_bounds__(256) void wconv_hist_kernel(
    const float* __restrict__ a, const float* __restrict__ b,
    const float* __restrict__ c, const float* __restrict__ d,
    const float* __restrict__ e, unsigned short* __restrict__ o,
    const int* __restrict__ eid, int* __restrict__ cnt,
    int* __restrict__ rank, int E)
{
    int blk = blockIdx.x;
    if (blk < 320) {
        int i = blk * 256 + threadIdx.x;       // 5*16384 total
        int w = i >> 14, j = i & 16383;
        const float* p = (w == 0) ? a : (w == 1) ? b : (w == 2) ? c : (w == 3) ? d : e;
        o[i] = f2bf(p[j]);
    } else {
        int i = (blk - 320) * 256 + threadIdx.x;
        if (i < E) rank[i] = atomicAdd(&cnt[eid[i]], 1);
    }
}

__global__ __launch_bounds__(256) void scan1_kernel(
    const int* __restrict__ cnt, int* __restrict__ bsum, int n)
{
    int base = blockIdx.x * 1024;
    int s = 0;
    #pragma unroll
    for (int p = 0; p < 4; ++p) {
        int i = base + (int)threadIdx.x + p * 256;
        if (i < n) s += cnt[i];
    }
    #pragma unroll
    for (int m = 1; m <= 32; m <<= 1) s += __shfl_xor(s, m, 64);
    __shared__ int ws_[4];
    int wid = threadIdx.x >> 6;
    if ((threadIdx.x & 63) == 0) ws_[wid] = s;
    __syncthreads();
    if (threadIdx.x == 0) bsum[blockIdx.x] = ws_[0] + ws_[1] + ws_[2] + ws_[3];
}

// ======= merged: scan3 (blocks 0..nb-1) ∥ LN+GELU (rest) ===================
__global__ __launch_bounds__(256) void scan3_ln_kernel(
    const int* __restrict__ cnt, const int* __restrict__ bsum,
    int* __restrict__ row_start, int n, int nb,
    const float* __restrict__ in_feats, const float* __restrict__ gamma,
    const float* __restrict__ beta, unsigned short* __restrict__ deltab, int M)
{
    int blk = blockIdx.x;
    if (blk < nb) {
        __shared__ int base_off;
        int tid = threadIdx.x, lane = tid & 63, wid = tid >> 6;
        if (tid == 0) {
            int a = 0;
            for (int j = 0; j < blk; ++j) a += bsum[j];
            base_off = a;
            if (blk == nb - 1) {
                int tot = a;
                for (int j = blk; j < nb; ++j) tot += bsum[j];
                row_start[n] = tot;
            }
        }
        int base = blk * 1024;
        int v[4]; int s = 0;
        #pragma unroll
        for (int p = 0; p < 4; ++p) {
            int i = base + tid * 4 + p;
            v[p] = (i < n) ? cnt[i] : 0;
            s += v[p];
        }
        int ss = s;
        #pragma unroll
        for (int off = 1; off < 64; off <<= 1) {
            int t = __shfl_up(ss, off, 64);
            if (lane >= off) ss += t;
        }
        __shared__ int wsum[4];
        if (lane == 63) wsum[wid] = ss;
        __syncthreads();
        int woff = 0;
        for (int j = 0; j < wid; ++j) woff += wsum[j];
        int a = base_off + woff + (ss - s);
        #pragma unroll
        for (int p = 0; p < 4; ++p) {
            int i = base + tid * 4 + p;
            if (i < n) { row_start[i] = a; a += v[p]; }
        }
        return;
    }
    // ---- LN + GELU (4 threads/row) ----
    int li = (blk - nb) * 256 + threadIdx.x;
    int row = li >> 2, t4 = li & 3;
    if (row >= M) return;
    size_t rbase = (size_t)row * NF;

    const float4* ip = (const float4*)(in_feats + rbase) + t4 * 8;
    float4 xf[8];
    #pragma unroll
    for (int p = 0; p < 8; ++p) xf[p] = ip[p];
    float s = 0.f, sq = 0.f;
    #pragma unroll
    for (int p = 0; p < 8; ++p) {
        s  += xf[p].x + xf[p].y + xf[p].z + xf[p].w;
        sq += xf[p].x * xf[p].x + xf[p].y * xf[p].y
            + xf[p].z * xf[p].z + xf[p].w * xf[p].w;
    }
    s  += __shfl_xor(s, 1, 64);  s  += __shfl_xor(s, 2, 64);
    sq += __shfl_xor(sq, 1, 64); sq += __shfl_xor(sq, 2, 64);
    float mu = s * (1.0f / 128.0f);
    float var = sq * (1.0f / 128.0f) - mu * mu;
    float rstd = rsqrtf(var + 1e-5f);

    const float4* gp = (const float4*)gamma + t4 * 8;
    const float4* bp = (const float4*)beta + t4 * 8;
    uint dreg[16];
    #pragma unroll
    for (int p = 0; p < 8; ++p) {
        float4 g4 = gp[p], b4 = bp[p];
        float o0 = (xf[p].x - mu) * rstd * g4.x + b4.x;
        float o1 = (xf[p].y - mu) * rstd * g4.y + b4.y;
        float o2 = (xf[p].z - mu) * rstd * g4.z + b4.z;
        float o3 = (xf[p].w - mu) * rstd * g4.w + b4.w;
        o0 = 0.5f * o0 * (1.0f + erff(o0 * 0.70710678118654752f));
        o1 = 0.5f * o1 * (1.0f + erff(o1 * 0.70710678118654752f));
        o2 = 0.5f * o2 * (1.0f + erff(o2 * 0.70710678118654752f));
        o3 = 0.5f * o3 * (1.0f + erff(o3 * 0.70710678118654752f));
        ushort4 h = pack4(o0, o1, o2, o3);
        dreg[p * 2]     = (uint)h.x | ((uint)h.y << 16);
        dreg[p * 2 + 1] = (uint)h.z | ((uint)h.w << 16);
    }
    uint4* od = (uint4*)(deltab + rbase + t4 * 32);
    #pragma unroll
    for (int q = 0; q < 4; ++q)
        od[q] = make_uint4(dreg[q*4], dreg[q*4+1], dreg[q*4+2], dreg[q*4+3]);
}

// ======= merged: scatter (blocks 0..sb-1) ∥ gemm_dv (rest) =====
// scatter stores via nontemporal 8B writes (bypass L2 dirty-line allocation
// -> less partial-line writeback amplification). dv role = round-8 proven.
__global__ __launch_bounds__(256) void scatter_dv_kernel(
    const int* __restrict__ eid, const float* __restrict__ ew,
    const int* __restrict__ row_start, const int* __restrict__ rank,
    int2* __restrict__ edata, int E, int sb,
    const float* __restrict__ struc, const unsigned short* __restrict__ deltab,
    const unsigned short* __restrict__ Wall, const float* __restrict__ bs,
    const float* __restrict__ bv, unsigned short* __restrict__ dstrb,
    unsigned short* __restrict__ kvb, int M, int nt, int ndv)
{
    __shared__ unsigned short Wl[128][136];
    __shared__ unsigned short Cst[64][136];

    int blk = blockIdx.x;
    if (blk < sb) {    // ---- scatter role (no LDS use) ----
        int i = blk * 256 + threadIdx.x;
        if (i < E) {
            int src = eid[i];
            int pos = row_start[src] + rank[i];
            unsigned long long v = (unsigned long long)(unsigned int)eid[E + i]
                                 | ((unsigned long long)__float_as_uint(ew[i]) << 32);
            __builtin_nontemporal_store(v, (unsigned long long*)&edata[pos]);
        }
        return;
    }

    // ---- gemm_dv role ----
    int idx = blk - sb;            // 0..2*ndv-1
    int y = idx / ndv;             // 0=dstr 1=v
    int xb = idx % ndv;

    int tid = threadIdx.x;
    int lane = tid & 63, w = tid >> 6, lg = lane & 15, quad = lane >> 4;

    const unsigned short* Wg = Wall + ((y == 0) ? 0 : 3 * 16384);  // Ws or Wv
    const float* bias = (y == 0) ? bs : bv;
    unsigned short* outg = (y == 0) ? dstrb : (kvb + NF);
    int ostride = (y == 0) ? NF : 2 * NF;

    {
        const uint4* g = (const uint4*)Wg;
        #pragma unroll
        for (int p = 0; p < 8; ++p) {
            int i2 = tid + p * 256;
            *(uint4*)&Wl[i2 >> 4][(i2 & 15) * 8] = g[i2];
        }
    }
    float br[8];
    #pragma unroll
    for (int t = 0; t < 8; ++t) br[t] = bias[t * 16 + lg];
    __syncthreads();   // the only barrier

    for (int tile = xb; tile < nt; tile += ndv) {
        int m0 = tile * 64;
        int am = m0 + w * 16 + lg;
        size_t rb = (size_t)(am < M ? am : 0) * NF;

        short8 af[4];
        if (y == 0) {   // struc fp32 -> bf16 A-frags
            const float4* sp = (const float4*)(struc + rb);
            #pragma unroll
            for (int ks = 0; ks < 4; ++ks) {
                float4 f0 = sp[ks * 8 + quad * 2];
                float4 f1 = sp[ks * 8 + quad * 2 + 1];
                ushort4 h0 = pack4(f0.x, f0.y, f0.z, f0.w);
                ushort4 h1 = pack4(f1.x, f1.y, f1.z, f1.w);
                uint4 pk = make_uint4((uint)h0.x | ((uint)h0.y << 16),
                                      (uint)h0.z | ((uint)h0.w << 16),
                                      (uint)h1.x | ((uint)h1.y << 16),
                                      (uint)h1.z | ((uint)h1.w << 16));
                af[ks] = *(short8*)&pk;
            }
        } else {
            const unsigned short* arow = deltab + rb + quad * 8;
            #pragma unroll
            for (int ks = 0; ks < 4; ++ks) af[ks] = *(const short8*)(arow + ks * 32);
        }

        floatx4 acc[8];
        #pragma unroll
        for (int t = 0; t < 8; ++t) acc[t] = (floatx4){0.f, 0.f, 0.f, 0.f};
        #pragma unroll
        for (int ks = 0; ks < 4; ++ks) {
            #pragma unroll
            for (int t = 0; t < 8; ++t) {
                short8 b = *(const short8*)&Wl[t * 16 + lg][ks * 32 + quad * 8];
                acc[t] = __builtin_amdgcn_mfma_f32_16x16x32_bf16(af[ks], b, acc[t], 0, 0, 0);
            }
        }

        // epilogue
        if (y == 0) {
            #pragma unroll
            for (int t = 0; t < 8; ++t) {
                int col = t * 16 + lg;
                #pragma unroll
                for (int r = 0; r < 4; ++r) {
                    int gm = m0 + w * 16 + quad * 4 + r;
                    float dadd = bf2f(deltab[(size_t)(gm < M ? gm : 0) * NF + col]);
                    Cst[w * 16 + quad * 4 + r][col] = f2bf(acc[t][r] + br[t] + dadd);
                }
            }
        } else {
            #pragma unroll
            for (int t = 0; t < 8; ++t) {
                int col = t * 16 + lg;
                #pragma unroll
                for (int r = 0; r < 4; ++r)
                    Cst[w * 16 + quad * 4 + r][col] = f2bf(acc[t][r] + br[t]);
            }
        }
        #pragma unroll
        for (int p = 0; p < 4; ++p) {
            int i2 = lane + p * 64;
            int row = w * 16 + (i2 >> 4), c16 = i2 & 15;
            int gm = m0 + row;
            if (gm < M)
                *(uint4*)(outg + (size_t)gm * ostride + c16 * 8) = *(const uint4*)&Cst[row][c16 * 8];
        }
    }
}

// ========== gemm_qk (LDS W, grid-stride — round-8 proven) ==================
__global__ __launch_bounds__(256) void gemm_qk_kernel(
    const unsigned short* __restrict__ dstrb, const unsigned short* __restrict__ Wall,
    const float* __restrict__ bq, const float* __restrict__ bk,
    unsigned short* __restrict__ qb, unsigned short* __restrict__ kvb,
    int M, int nt)
{
    __shared__ unsigned short Wl[128][136];
    __shared__ unsigned short Cst[64][136];

    int tid = threadIdx.x;
    int y = blockIdx.y;                       // 0=q 1=k
    int lane = tid & 63, w = tid >> 6, lg = lane & 15, quad = lane >> 4;

    const unsigned short* Wg = Wall + (y + 1) * 16384;   // Wq or Wk
    const float* bias = (y == 0) ? bq : bk;
    float scale = (y == 0) ? 0.25f : 1.0f;
    unsigned short* outg = (y == 0) ? qb : kvb;
    int ostride = (y == 0) ? NF : 2 * NF;

    {
        const uint4* g = (const uint4*)Wg;
        #pragma unroll
        for (int p = 0; p < 8; ++p) {
            int idx = tid + p * 256;
            *(uint4*)&Wl[idx >> 4][(idx & 15) * 8] = g[idx];
        }
    }
    float br[8];
    #pragma unroll
    for (int t = 0; t < 8; ++t) br[t] = bias[t * 16 + lg] * scale;
    __syncthreads();   // the only barrier

    for (int tile = blockIdx.x; tile < nt; tile += gridDim.x) {
        int m0 = tile * 64;
        int am = m0 + w * 16 + lg;
        const unsigned short* arow = dstrb + (size_t)(am < M ? am : 0) * NF + quad * 8;

        floatx4 acc[8];
        #pragma unroll
        for (int t = 0; t < 8; ++t) acc[t] = (floatx4){0.f, 0.f, 0.f, 0.f};
        short8 af[4];
        #pragma unroll
        for (int ks = 0; ks < 4; ++ks) af[ks] = *(const short8*)(arow + ks * 32);
        #pragma unroll
        for (int ks = 0; ks < 4; ++ks) {
            #pragma unroll
            for (int t = 0; t < 8; ++t) {
                short8 b = *(const short8*)&Wl[t * 16 + lg][ks * 32 + quad * 8];
                acc[t] = __builtin_amdgcn_mfma_f32_16x16x32_bf16(af[ks], b, acc[t], 0, 0, 0);
            }
        }
        #pragma unroll
        for (int t = 0; t < 8; ++t) {
            int col = t * 16 + lg;
            #pragma unroll
            for (int r = 0; r < 4; ++r)
                Cst[w * 16 + quad * 4 + r][col] = f2bf(acc[t][r] * scale + br[t]);
        }
        #pragma unroll
        for (int p = 0; p < 4; ++p) {
            int idx = lane + p * 64;
            int row = w * 16 + (idx >> 4), c16 = idx & 15;
            int gm = m0 + row;
            if (gm < M)
                *(uint4*)(outg + (size_t)gm * ostride + c16 * 8) = *(const uint4*)&Cst[row][c16 * 8];
        }
    }
}

// ================= out-proj: out = in_feats + agg @ Wo^T =================
__global__ __launch_bounds__(256) void gemm_out_kernel(
    const unsigned short* __restrict__ Xb, const unsigned short* __restrict__ Wb,
    const float* __restrict__ addf, float* __restrict__ Y, int M, int nt)
{
    __shared__ unsigned short Wl[128][136];
    int tid = threadIdx.x;
    int lane = tid & 63, w = tid >> 6, lg = lane & 15, quad = lane >> 4;

    {
        const uint4* g = (const uint4*)Wb;
        #pragma unroll
        for (int p = 0; p < 8; ++p) {
            int idx = tid + p * 256;
            *(uint4*)&Wl[idx >> 4][(idx & 15) * 8] = g[idx];
        }
    }
    __syncthreads();

    for (int tile = blockIdx.x; tile < nt; tile += gridDim.x) {
        int m0 = tile * 64;
        int am = m0 + w * 16 + lg;
        const unsigned short* arow = Xb + (size_t)(am < M ? am : 0) * NF + quad * 8;

        floatx4 acc[8];
        #pragma unroll
        for (int t = 0; t < 8; ++t) acc[t] = (floatx4){0.f, 0.f, 0.f, 0.f};
        short8 af[4];
        #pragma unroll
        for (int ks = 0; ks < 4; ++ks) af[ks] = *(const short8*)(arow + ks * 32);
        #pragma unroll
        for (int ks = 0; ks < 4; ++ks) {
            #pragma unroll
            for (int t = 0; t < 8; ++t) {
                short8 b = *(const short8*)&Wl[t * 16 + lg][ks * 32 + quad * 8];
                acc[t] = __builtin_amdgcn_mfma_f32_16x16x32_bf16(af[ks], b, acc[t], 0, 0, 0);
            }
        }
        // fp32 epilogue: per (t,r) 16 lanes write 64B contiguous
        #pragma unroll
        for (int t = 0; t < 8; ++t) {
            int col = t * 16 + lg;
            #pragma unroll
            for (int r = 0; r < 4; ++r) {
                int gm = m0 + w * 16 + quad * 4 + r;
                if (gm >= M) continue;
                size_t off = (size_t)gm * NF + col;
                Y[off] = acc[t][r] + addf[off];
            }
        }
    }
}

// ---------------- per-node attention aggregation (round-0 proven) ---------
__global__ __launch_bounds__(256) void aggregate_kernel(
    const unsigned short* __restrict__ Q, const unsigned short* __restrict__ kvb,
    const int* __restrict__ row_start, const int2* __restrict__ edata,
    unsigned short* __restrict__ agg, int N)
{
    int node = blockIdx.x * 4 + (threadIdx.x >> 6);
    if (node >= N) return;
    int lane = threadIdx.x & 63;
    int sg = lane >> 4, lg = lane & 15;
    int rs = row_start[node], re = row_start[node + 1];

    float qv[8];
    unpack8(*(const uint4*)(Q + (size_t)node * NF + lg * 8), qv);
    float acc[8];
    #pragma unroll
    for (int j = 0; j < 8; ++j) acc[j] = 0.f;

    int e1 = rs + sg, e2 = rs + sg + 4;
    int2 ed1 = (e1 < re) ? edata[e1] : make_int2(0, 0);
    int2 ed2 = (e2 < re) ? edata[e2] : make_int2(0, 0);

    for (int e0 = rs; e0 < re; e0 += 8) {
        int2 c1 = ed1, c2 = ed2;
        int en1 = e0 + 8 + sg, en2 = en1 + 4;
        ed1 = (en1 < re) ? edata[en1] : make_int2(0, 0);
        ed2 = (en2 < re) ? edata[en2] : make_int2(0, 0);

        // issue all 4 gathers up front (K,V adjacent lines per edge)
        const uint4* p1 = (const uint4*)kvb + (size_t)c1.x * 32 + lg;
        const uint4* p2 = (const uint4*)kvb + (size_t)c2.x * 32 + lg;
        uint4 k1u = p1[0], v1u = p1[16];
        uint4 k2u = p2[0], v2u = p2[16];

        float kv1[8], kv2[8];
        unpack8(k1u, kv1);
        unpack8(k2u, kv2);
        float s1 = qv[0] * kv1[0], s2 = qv[0] * kv2[0];
        #pragma unroll
        for (int j = 1; j < 8; ++j) {
            s1 = fmaf(qv[j], kv1[j], s1);
            s2 = fmaf(qv[j], kv2[j], s2);
        }
        s1 += __shfl_xor(s1, 1, 64);    // head = 16 feats = 2 adjacent lanes
        s2 += __shfl_xor(s2, 1, 64);
        float a1 = __int_as_float(c1.y) / (1.f + __expf(-s1));
        float a2 = __int_as_float(c2.y) / (1.f + __expf(-s2));

        float vv1[8], vv2[8];
        unpack8(v1u, vv1);
        unpack8(v2u, vv2);
        #pragma unroll
        for (int j = 0; j < 8; ++j) {
            acc[j] = fmaf(a1, vv1[j], acc[j]);
            acc[j] = fmaf(a2, vv2[j], acc[j]);
        }
    }
    #pragma unroll
    for (int j = 0; j < 8; ++j) {
        acc[j] += __shfl_xor(acc[j], 16, 64);
        acc[j] += __shfl_xor(acc[j], 32, 64);
    }
    if (sg == 0) {
        unsigned short* o = agg + (size_t)node * NF + lg * 8;
        *(ushort4*)o       = pack4(acc[0], acc[1], acc[2], acc[3]);
        *(ushort4*)(o + 4) = pack4(acc[4], acc[5], acc[6], acc[7]);
    }
}

extern "C" void kernel_launch(void* const* d_in, const int* in_sizes, int n_in,
                              void* d_out, int out_size, void* d_ws, size_t ws_size,
                              hipStream_t stream)
{
    const float* in_feats = (const float*)d_in[0];
    const float* struc    = (const float*)d_in[1];
    const float* eweights = (const float*)d_in[2];
    const float* ln_scale = (const float*)d_in[3];
    const float* ln_bias  = (const float*)d_in[4];
    const float* Ws       = (const float*)d_in[5];
    const float* bs       = (const float*)d_in[6];
    const float* Wq       = (const float*)d_in[7];
    const float* bq       = (const float*)d_in[8];
    const float* Wk       = (const float*)d_in[9];
    const float* bk       = (const float*)d_in[10];
    const float* Wv       = (const float*)d_in[11];
    const float* bv       = (const float*)d_in[12];
    const float* Wo       = (const float*)d_in[13];
    const int*   edge_ids = (const int*)d_in[14];
    float* out = (float*)d_out;

    int N = in_sizes[0] / NF;   // 50000
    int E = in_sizes[2];        // 800000

    // ---- workspace
    size_t F = (size_t)N * NF;
    unsigned short* deltab = (unsigned short*)d_ws;
    unsigned short* dstrb  = deltab + F;
    unsigned short* qb     = dstrb + F;
    unsigned short* kvb    = qb + F;            // 2F: [K|V] interleaved per node
    unsigned short* aggb   = kvb + 2 * F;
    unsigned short* Wall   = aggb + F;          // 5*16384: Ws,Wq,Wk,Wv,Wo
    int2*  edata     = (int2*)(Wall + 5 * 16384);
    int*   cnt       = (int*)(edata + E);
    int*   row_start = cnt + N;                 // N+1
    int*   bsum      = row_start + N + 1;       // 64
    int*   rank      = bsum + 64;               // E

    int nt  = (N + 63) / 64;    // 782 row-tiles
    int geb = (E + 255) / 256;  // 3125 edge blocks
    int nb  = (N + 1023) / 1024;
    int ppb = (N * 4 + 255) / 256;  // 782 LN blocks
    int ndv = 261;                  // dv blocks per y-slice

    // cnt -> 0, then weights-convert ∥ histogram (one dispatch)
    hipMemsetAsync(cnt, 0, (size_t)N * sizeof(int), stream);
    wconv_hist_kernel<<<320 + geb, 256, 0, stream>>>(Ws, Wq, Wk, Wv, Wo, Wall,
                                                     edge_ids, cnt, rank, E);

    scan1_kernel<<<nb, 256, 0, stream>>>(cnt, bsum, N);

    // scan3 ∥ LN+GELU (one dispatch; independent work)
    scan3_ln_kernel<<<nb + ppb, 256, 0, stream>>>(cnt, bsum, row_start, N, nb,
                                                  in_feats, ln_scale, ln_bias,
                                                  deltab, N);

    // scatter ∥ gemm_dv (one dispatch; nt-store scatter, writeback drains under MFMA)
    scatter_dv_kernel<<<geb + 2 * ndv, 256, 0, stream>>>(edge_ids, eweights,
                                                         row_start, rank, edata, E, geb,
                                                         struc, deltab, Wall, bs, bv,
                                                         dstrb, kvb, N, nt, ndv);

    gemm_qk_kernel<<<dim3(261, 2), 256, 0, stream>>>(dstrb, Wall, bq, bk,
                                                     qb, kvb, N, nt);

    // edge attention + segment-sum
    aggregate_kernel<<<(N + 3) / 4, 256, 0, stream>>>(qb, kvb, row_start, edata, aggb, N);

    // out = in_feats + agg @ Wo^T
    gemm_out_kernel<<<nt, 256, 0, stream>>>(aggb, Wall + 4 * 16384, in_feats, out, N, nt);
}

// Round 12
// 286.690 us; speedup vs baseline: 1.5561x; 1.0462x over previous
//
#include <hip/hip_runtime.h>
#include <math.h>

#define NF 128

typedef __attribute__((ext_vector_type(8))) short short8;
typedef __attribute__((ext_vector_type(4))) float floatx4;

__device__ __forceinline__ unsigned short f2bf(float f) {
    union { float x; unsigned int i; } c; c.x = f;
    unsigned int r = c.i + 0x7fffu + ((c.i >> 16) & 1u);   // RNE
    return (unsigned short)(r >> 16);
}
__device__ __forceinline__ float bf2f(unsigned short u) {
    union { unsigned int i; float x; } c; c.i = ((unsigned int)u) << 16;
    return c.x;
}
__device__ __forceinline__ void unpack8(uint4 u, float* f) {
    union { unsigned int i; float x; } c;
    c.i = u.x << 16;          f[0] = c.x;
    c.i = u.x & 0xffff0000u;  f[1] = c.x;
    c.i = u.y << 16;          f[2] = c.x;
    c.i = u.y & 0xffff0000u;  f[3] = c.x;
    c.i = u.z << 16;          f[4] = c.x;
    c.i = u.z & 0xffff0000u;  f[5] = c.x;
    c.i = u.w << 16;          f[6] = c.x;
    c.i = u.w & 0xffff0000u;  f[7] = c.x;
}
__device__ __forceinline__ ushort4 pack4(float a, float b, float c, float d) {
    ushort4 h; h.x = f2bf(a); h.y = f2bf(b); h.z = f2bf(c); h.w = f2bf(d);
    return h;
}

// ======= merged: fp32->bf16 weight convert (blocks 0..319) ∥ hist (rest) ====
__global__ __launch_bounds__(256) void wconv_hist_kernel(
    const float* __restrict__ a, const float* __restrict__ b,
    const float* __restrict__ c, const float* __restrict__ d,
    const float* __restrict__ e, unsigned short* __restrict__ o,
    const int* __restrict__ eid, int* __restrict__ cnt,
    int* __restrict__ rank, int E)
{
    int blk = blockIdx.x;
    if (blk < 320) {
        int i = blk * 256 + threadIdx.x;       // 5*16384 total
        int w = i >> 14, j = i & 16383;
        const float* p = (w == 0) ? a : (w == 1) ? b : (w == 2) ? c : (w == 3) ? d : e;
        o[i] = f2bf(p[j]);
    } else {
        int i = (blk - 320) * 256 + threadIdx.x;
        if (i < E) rank[i] = atomicAdd(&cnt[eid[i]], 1);
    }
}

__global__ __launch_bounds__(256) void scan1_kernel(
    const int* __restrict__ cnt, int* __restrict__ bsum, int n)
{
    int base = blockIdx.x * 1024;
    int s = 0;
    #pragma unroll
    for (int p = 0; p < 4; ++p) {
        int i = base + (int)threadIdx.x + p * 256;
        if (i < n) s += cnt[i];
    }
    #pragma unroll
    for (int m = 1; m <= 32; m <<= 1) s += __shfl_xor(s, m, 64);
    __shared__ int ws_[4];
    int wid = threadIdx.x >> 6;
    if ((threadIdx.x & 63) == 0) ws_[wid] = s;
    __syncthreads();
    if (threadIdx.x == 0) bsum[blockIdx.x] = ws_[0] + ws_[1] + ws_[2] + ws_[3];
}

// ======= merged: scan3 (blocks 0..nb-1) ∥ LN+GELU (rest) ===================
__global__ __launch_bounds__(256) void scan3_ln_kernel(
    const int* __restrict__ cnt, const int* __restrict__ bsum,
    int* __restrict__ row_start, int n, int nb,
    const float* __restrict__ in_feats, const float* __restrict__ gamma,
    const float* __restrict__ beta, unsigned short* __restrict__ deltab, int M)
{
    int blk = blockIdx.x;
    if (blk < nb) {
        __shared__ int base_off;
        int tid = threadIdx.x, lane = tid & 63, wid = tid >> 6;
        if (tid == 0) {
            int a = 0;
            for (int j = 0; j < blk; ++j) a += bsum[j];
            base_off = a;
            if (blk == nb - 1) {
                int tot = a;
                for (int j = blk; j < nb; ++j) tot += bsum[j];
                row_start[n] = tot;
            }
        }
        int base = blk * 1024;
        int v[4]; int s = 0;
        #pragma unroll
        for (int p = 0; p < 4; ++p) {
            int i = base + tid * 4 + p;
            v[p] = (i < n) ? cnt[i] : 0;
            s += v[p];
        }
        int ss = s;
        #pragma unroll
        for (int off = 1; off < 64; off <<= 1) {
            int t = __shfl_up(ss, off, 64);
            if (lane >= off) ss += t;
        }
        __shared__ int wsum[4];
        if (lane == 63) wsum[wid] = ss;
        __syncthreads();
        int woff = 0;
        for (int j = 0; j < wid; ++j) woff += wsum[j];
        int a = base_off + woff + (ss - s);
        #pragma unroll
        for (int p = 0; p < 4; ++p) {
            int i = base + tid * 4 + p;
            if (i < n) { row_start[i] = a; a += v[p]; }
        }
        return;
    }
    // ---- LN + GELU (4 threads/row) ----
    int li = (blk - nb) * 256 + threadIdx.x;
    int row = li >> 2, t4 = li & 3;
    if (row >= M) return;
    size_t rbase = (size_t)row * NF;

    const float4* ip = (const float4*)(in_feats + rbase) + t4 * 8;
    float4 xf[8];
    #pragma unroll
    for (int p = 0; p < 8; ++p) xf[p] = ip[p];
    float s = 0.f, sq = 0.f;
    #pragma unroll
    for (int p = 0; p < 8; ++p) {
        s  += xf[p].x + xf[p].y + xf[p].z + xf[p].w;
        sq += xf[p].x * xf[p].x + xf[p].y * xf[p].y
            + xf[p].z * xf[p].z + xf[p].w * xf[p].w;
    }
    s  += __shfl_xor(s, 1, 64);  s  += __shfl_xor(s, 2, 64);
    sq += __shfl_xor(sq, 1, 64); sq += __shfl_xor(sq, 2, 64);
    float mu = s * (1.0f / 128.0f);
    float var = sq * (1.0f / 128.0f) - mu * mu;
    float rstd = rsqrtf(var + 1e-5f);

    const float4* gp = (const float4*)gamma + t4 * 8;
    const float4* bp = (const float4*)beta + t4 * 8;
    uint dreg[16];
    #pragma unroll
    for (int p = 0; p < 8; ++p) {
        float4 g4 = gp[p], b4 = bp[p];
        float o0 = (xf[p].x - mu) * rstd * g4.x + b4.x;
        float o1 = (xf[p].y - mu) * rstd * g4.y + b4.y;
        float o2 = (xf[p].z - mu) * rstd * g4.z + b4.z;
        float o3 = (xf[p].w - mu) * rstd * g4.w + b4.w;
        o0 = 0.5f * o0 * (1.0f + erff(o0 * 0.70710678118654752f));
        o1 = 0.5f * o1 * (1.0f + erff(o1 * 0.70710678118654752f));
        o2 = 0.5f * o2 * (1.0f + erff(o2 * 0.70710678118654752f));
        o3 = 0.5f * o3 * (1.0f + erff(o3 * 0.70710678118654752f));
        ushort4 h = pack4(o0, o1, o2, o3);
        dreg[p * 2]     = (uint)h.x | ((uint)h.y << 16);
        dreg[p * 2 + 1] = (uint)h.z | ((uint)h.w << 16);
    }
    uint4* od = (uint4*)(deltab + rbase + t4 * 32);
    #pragma unroll
    for (int q = 0; q < 4; ++q)
        od[q] = make_uint4(dreg[q*4], dreg[q*4+1], dreg[q*4+2], dreg[q*4+3]);
}

// ======= merged: scatter (blocks 0..sb-1) ∥ gemm_dv (rest) — round-8 proven =
__global__ __launch_bounds__(256) void scatter_dv_kernel(
    const int* __restrict__ eid, const float* __restrict__ ew,
    const int* __restrict__ row_start, const int* __restrict__ rank,
    int2* __restrict__ edata, int E, int sb,
    const float* __restrict__ struc, const unsigned short* __restrict__ deltab,
    const unsigned short* __restrict__ Wall, const float* __restrict__ bs,
    const float* __restrict__ bv, unsigned short* __restrict__ dstrb,
    unsigned short* __restrict__ kvb, int M, int nt, int ndv)
{
    __shared__ unsigned short Wl[128][136];
    __shared__ unsigned short Cst[64][136];

    int blk = blockIdx.x;
    if (blk < sb) {    // ---- scatter role (no LDS use) ----
        int i = blk * 256 + threadIdx.x;
        if (i < E) {
            int src = eid[i];
            int pos = row_start[src] + rank[i];
            edata[pos] = make_int2(eid[E + i], __float_as_int(ew[i]));
        }
        return;
    }

    // ---- gemm_dv role ----
    int idx = blk - sb;            // 0..2*ndv-1
    int y = idx / ndv;             // 0=dstr 1=v
    int xb = idx % ndv;

    int tid = threadIdx.x;
    int lane = tid & 63, w = tid >> 6, lg = lane & 15, quad = lane >> 4;

    const unsigned short* Wg = Wall + ((y == 0) ? 0 : 3 * 16384);  // Ws or Wv
    const float* bias = (y == 0) ? bs : bv;
    unsigned short* outg = (y == 0) ? dstrb : (kvb + NF);
    int ostride = (y == 0) ? NF : 2 * NF;

    {
        const uint4* g = (const uint4*)Wg;
        #pragma unroll
        for (int p = 0; p < 8; ++p) {
            int i2 = tid + p * 256;
            *(uint4*)&Wl[i2 >> 4][(i2 & 15) * 8] = g[i2];
        }
    }
    float br[8];
    #pragma unroll
    for (int t = 0; t < 8; ++t) br[t] = bias[t * 16 + lg];
    __syncthreads();   // the only barrier

    for (int tile = xb; tile < nt; tile += ndv) {
        int m0 = tile * 64;
        int am = m0 + w * 16 + lg;
        size_t rb = (size_t)(am < M ? am : 0) * NF;

        short8 af[4];
        if (y == 0) {   // struc fp32 -> bf16 A-frags
            const float4* sp = (const float4*)(struc + rb);
            #pragma unroll
            for (int ks = 0; ks < 4; ++ks) {
                float4 f0 = sp[ks * 8 + quad * 2];
                float4 f1 = sp[ks * 8 + quad * 2 + 1];
                ushort4 h0 = pack4(f0.x, f0.y, f0.z, f0.w);
                ushort4 h1 = pack4(f1.x, f1.y, f1.z, f1.w);
                uint4 pk = make_uint4((uint)h0.x | ((uint)h0.y << 16),
                                      (uint)h0.z | ((uint)h0.w << 16),
                                      (uint)h1.x | ((uint)h1.y << 16),
                                      (uint)h1.z | ((uint)h1.w << 16));
                af[ks] = *(short8*)&pk;
            }
        } else {
            const unsigned short* arow = deltab + rb + quad * 8;
            #pragma unroll
            for (int ks = 0; ks < 4; ++ks) af[ks] = *(const short8*)(arow + ks * 32);
        }

        floatx4 acc[8];
        #pragma unroll
        for (int t = 0; t < 8; ++t) acc[t] = (floatx4){0.f, 0.f, 0.f, 0.f};
        #pragma unroll
        for (int ks = 0; ks < 4; ++ks) {
            #pragma unroll
            for (int t = 0; t < 8; ++t) {
                short8 b = *(const short8*)&Wl[t * 16 + lg][ks * 32 + quad * 8];
                acc[t] = __builtin_amdgcn_mfma_f32_16x16x32_bf16(af[ks], b, acc[t], 0, 0, 0);
            }
        }

        // epilogue
        if (y == 0) {
            #pragma unroll
            for (int t = 0; t < 8; ++t) {
                int col = t * 16 + lg;
                #pragma unroll
                for (int r = 0; r < 4; ++r) {
                    int gm = m0 + w * 16 + quad * 4 + r;
                    float dadd = bf2f(deltab[(size_t)(gm < M ? gm : 0) * NF + col]);
                    Cst[w * 16 + quad * 4 + r][col] = f2bf(acc[t][r] + br[t] + dadd);
                }
            }
        } else {
            #pragma unroll
            for (int t = 0; t < 8; ++t) {
                int col = t * 16 + lg;
                #pragma unroll
                for (int r = 0; r < 4; ++r)
                    Cst[w * 16 + quad * 4 + r][col] = f2bf(acc[t][r] + br[t]);
            }
        }
        #pragma unroll
        for (int p = 0; p < 4; ++p) {
            int i2 = lane + p * 64;
            int row = w * 16 + (i2 >> 4), c16 = i2 & 15;
            int gm = m0 + row;
            if (gm < M)
                *(uint4*)(outg + (size_t)gm * ostride + c16 * 8) = *(const uint4*)&Cst[row][c16 * 8];
        }
    }
}

// ========== gemm_qk (LDS W, grid-stride — round-8 proven) ==================
__global__ __launch_bounds__(256) void gemm_qk_kernel(
    const unsigned short* __restrict__ dstrb, const unsigned short* __restrict__ Wall,
    const float* __restrict__ bq, const float* __restrict__ bk,
    unsigned short* __restrict__ qb, unsigned short* __restrict__ kvb,
    int M, int nt)
{
    __shared__ unsigned short Wl[128][136];
    __shared__ unsigned short Cst[64][136];

    int tid = threadIdx.x;
    int y = blockIdx.y;                       // 0=q 1=k
    int lane = tid & 63, w = tid >> 6, lg = lane & 15, quad = lane >> 4;

    const unsigned short* Wg = Wall + (y + 1) * 16384;   // Wq or Wk
    const float* bias = (y == 0) ? bq : bk;
    float scale = (y == 0) ? 0.25f : 1.0f;
    unsigned short* outg = (y == 0) ? qb : kvb;
    int ostride = (y == 0) ? NF : 2 * NF;

    {
        const uint4* g = (const uint4*)Wg;
        #pragma unroll
        for (int p = 0; p < 8; ++p) {
            int idx = tid + p * 256;
            *(uint4*)&Wl[idx >> 4][(idx & 15) * 8] = g[idx];
        }
    }
    float br[8];
    #pragma unroll
    for (int t = 0; t < 8; ++t) br[t] = bias[t * 16 + lg] * scale;
    __syncthreads();   // the only barrier

    for (int tile = blockIdx.x; tile < nt; tile += gridDim.x) {
        int m0 = tile * 64;
        int am = m0 + w * 16 + lg;
        const unsigned short* arow = dstrb + (size_t)(am < M ? am : 0) * NF + quad * 8;

        floatx4 acc[8];
        #pragma unroll
        for (int t = 0; t < 8; ++t) acc[t] = (floatx4){0.f, 0.f, 0.f, 0.f};
        short8 af[4];
        #pragma unroll
        for (int ks = 0; ks < 4; ++ks) af[ks] = *(const short8*)(arow + ks * 32);
        #pragma unroll
        for (int ks = 0; ks < 4; ++ks) {
            #pragma unroll
            for (int t = 0; t < 8; ++t) {
                short8 b = *(const short8*)&Wl[t * 16 + lg][ks * 32 + quad * 8];
                acc[t] = __builtin_amdgcn_mfma_f32_16x16x32_bf16(af[ks], b, acc[t], 0, 0, 0);
            }
        }
        #pragma unroll
        for (int t = 0; t < 8; ++t) {
            int col = t * 16 + lg;
            #pragma unroll
            for (int r = 0; r < 4; ++r)
                Cst[w * 16 + quad * 4 + r][col] = f2bf(acc[t][r] * scale + br[t]);
        }
        #pragma unroll
        for (int p = 0; p < 4; ++p) {
            int idx = lane + p * 64;
            int row = w * 16 + (idx >> 4), c16 = idx & 15;
            int gm = m0 + row;
            if (gm < M)
                *(uint4*)(outg + (size_t)gm * ostride + c16 * 8) = *(const uint4*)&Cst[row][c16 * 8];
        }
    }
}

// ================= out-proj: out = in_feats + agg @ Wo^T =================
__global__ __launch_bounds__(256) void gemm_out_kernel(
    const unsigned short* __restrict__ Xb, const unsigned short* __restrict__ Wb,
    const float* __restrict__ addf, float* __restrict__ Y, int M, int nt)
{
    __shared__ unsigned short Wl[128][136];
    int tid = threadIdx.x;
    int lane = tid & 63, w = tid >> 6, lg = lane & 15, quad = lane >> 4;

    {
        const uint4* g = (const uint4*)Wb;
        #pragma unroll
        for (int p = 0; p < 8; ++p) {
            int idx = tid + p * 256;
            *(uint4*)&Wl[idx >> 4][(idx & 15) * 8] = g[idx];
        }
    }
    __syncthreads();

    for (int tile = blockIdx.x; tile < nt; tile += gridDim.x) {
        int m0 = tile * 64;
        int am = m0 + w * 16 + lg;
        const unsigned short* arow = Xb + (size_t)(am < M ? am : 0) * NF + quad * 8;

        floatx4 acc[8];
        #pragma unroll
        for (int t = 0; t < 8; ++t) acc[t] = (floatx4){0.f, 0.f, 0.f, 0.f};
        short8 af[4];
        #pragma unroll
        for (int ks = 0; ks < 4; ++ks) af[ks] = *(const short8*)(arow + ks * 32);
        #pragma unroll
        for (int ks = 0; ks < 4; ++ks) {
            #pragma unroll
            for (int t = 0; t < 8; ++t) {
                short8 b = *(const short8*)&Wl[t * 16 + lg][ks * 32 + quad * 8];
                acc[t] = __builtin_amdgcn_mfma_f32_16x16x32_bf16(af[ks], b, acc[t], 0, 0, 0);
            }
        }
        // fp32 epilogue: per (t,r) 16 lanes write 64B contiguous
        #pragma unroll
        for (int t = 0; t < 8; ++t) {
            int col = t * 16 + lg;
            #pragma unroll
            for (int r = 0; r < 4; ++r) {
                int gm = m0 + w * 16 + quad * 4 + r;
                if (gm >= M) continue;
                size_t off = (size_t)gm * NF + col;
                Y[off] = acc[t][r] + addf[off];
            }
        }
    }
}

// ---------------- per-node attention aggregation (round-0 proven) ---------
__global__ __launch_bounds__(256) void aggregate_kernel(
    const unsigned short* __restrict__ Q, const unsigned short* __restrict__ kvb,
    const int* __restrict__ row_start, const int2* __restrict__ edata,
    unsigned short* __restrict__ agg, int N)
{
    int node = blockIdx.x * 4 + (threadIdx.x >> 6);
    if (node >= N) return;
    int lane = threadIdx.x & 63;
    int sg = lane >> 4, lg = lane & 15;
    int rs = row_start[node], re = row_start[node + 1];

    float qv[8];
    unpack8(*(const uint4*)(Q + (size_t)node * NF + lg * 8), qv);
    float acc[8];
    #pragma unroll
    for (int j = 0; j < 8; ++j) acc[j] = 0.f;

    int e1 = rs + sg, e2 = rs + sg + 4;
    int2 ed1 = (e1 < re) ? edata[e1] : make_int2(0, 0);
    int2 ed2 = (e2 < re) ? edata[e2] : make_int2(0, 0);

    for (int e0 = rs; e0 < re; e0 += 8) {
        int2 c1 = ed1, c2 = ed2;
        int en1 = e0 + 8 + sg, en2 = en1 + 4;
        ed1 = (en1 < re) ? edata[en1] : make_int2(0, 0);
        ed2 = (en2 < re) ? edata[en2] : make_int2(0, 0);

        // issue all 4 gathers up front (K,V adjacent lines per edge)
        const uint4* p1 = (const uint4*)kvb + (size_t)c1.x * 32 + lg;
        const uint4* p2 = (const uint4*)kvb + (size_t)c2.x * 32 + lg;
        uint4 k1u = p1[0], v1u = p1[16];
        uint4 k2u = p2[0], v2u = p2[16];

        float kv1[8], kv2[8];
        unpack8(k1u, kv1);
        unpack8(k2u, kv2);
        float s1 = qv[0] * kv1[0], s2 = qv[0] * kv2[0];
        #pragma unroll
        for (int j = 1; j < 8; ++j) {
            s1 = fmaf(qv[j], kv1[j], s1);
            s2 = fmaf(qv[j], kv2[j], s2);
        }
        s1 += __shfl_xor(s1, 1, 64);    // head = 16 feats = 2 adjacent lanes
        s2 += __shfl_xor(s2, 1, 64);
        float a1 = __int_as_float(c1.y) / (1.f + __expf(-s1));
        float a2 = __int_as_float(c2.y) / (1.f + __expf(-s2));

        float vv1[8], vv2[8];
        unpack8(v1u, vv1);
        unpack8(v2u, vv2);
        #pragma unroll
        for (int j = 0; j < 8; ++j) {
            acc[j] = fmaf(a1, vv1[j], acc[j]);
            acc[j] = fmaf(a2, vv2[j], acc[j]);
        }
    }
    #pragma unroll
    for (int j = 0; j < 8; ++j) {
        acc[j] += __shfl_xor(acc[j], 16, 64);
        acc[j] += __shfl_xor(acc[j], 32, 64);
    }
    if (sg == 0) {
        unsigned short* o = agg + (size_t)node * NF + lg * 8;
        *(ushort4*)o       = pack4(acc[0], acc[1], acc[2], acc[3]);
        *(ushort4*)(o + 4) = pack4(acc[4], acc[5], acc[6], acc[7]);
    }
}

extern "C" void kernel_launch(void* const* d_in, const int* in_sizes, int n_in,
                              void* d_out, int out_size, void* d_ws, size_t ws_size,
                              hipStream_t stream)
{
    const float* in_feats = (const float*)d_in[0];
    const float* struc    = (const float*)d_in[1];
    const float* eweights = (const float*)d_in[2];
    const float* ln_scale = (const float*)d_in[3];
    const float* ln_bias  = (const float*)d_in[4];
    const float* Ws       = (const float*)d_in[5];
    const float* bs       = (const float*)d_in[6];
    const float* Wq       = (const float*)d_in[7];
    const float* bq       = (const float*)d_in[8];
    const float* Wk       = (const float*)d_in[9];
    const float* bk       = (const float*)d_in[10];
    const float* Wv       = (const float*)d_in[11];
    const float* bv       = (const float*)d_in[12];
    const float* Wo       = (const float*)d_in[13];
    const int*   edge_ids = (const int*)d_in[14];
    float* out = (float*)d_out;

    int N = in_sizes[0] / NF;   // 50000
    int E = in_sizes[2];        // 800000

    // ---- workspace
    size_t F = (size_t)N * NF;
    unsigned short* deltab = (unsigned short*)d_ws;
    unsigned short* dstrb  = deltab + F;
    unsigned short* qb     = dstrb + F;
    unsigned short* kvb    = qb + F;            // 2F: [K|V] interleaved per node
    unsigned short* aggb   = kvb + 2 * F;
    unsigned short* Wall   = aggb + F;          // 5*16384: Ws,Wq,Wk,Wv,Wo
    int2*  edata     = (int2*)(Wall + 5 * 16384);
    int*   cnt       = (int*)(edata + E);
    int*   row_start = cnt + N;                 // N+1
    int*   bsum      = row_start + N + 1;       // 64
    int*   rank      = bsum + 64;               // E

    int nt  = (N + 63) / 64;    // 782 row-tiles
    int geb = (E + 255) / 256;  // 3125 edge blocks
    int nb  = (N + 1023) / 1024;
    int ppb = (N * 4 + 255) / 256;  // 782 LN blocks
    int ndv = 384;  // dv blocks per y-slice: 2*384 = 768 = 256 CU x 3 blocks/CU

    // cnt -> 0, then weights-convert ∥ histogram (one dispatch)
    hipMemsetAsync(cnt, 0, (size_t)N * sizeof(int), stream);
    wconv_hist_kernel<<<320 + geb, 256, 0, stream>>>(Ws, Wq, Wk, Wv, Wo, Wall,
                                                     edge_ids, cnt, rank, E);

    scan1_kernel<<<nb, 256, 0, stream>>>(cnt, bsum, N);

    // scan3 ∥ LN+GELU (one dispatch; independent work)
    scan3_ln_kernel<<<nb + ppb, 256, 0, stream>>>(cnt, bsum, row_start, N, nb,
                                                  in_feats, ln_scale, ln_bias,
                                                  deltab, N);

    // scatter ∥ gemm_dv (one dispatch; scatter writeback drains under MFMA)
    scatter_dv_kernel<<<geb + 2 * ndv, 256, 0, stream>>>(edge_ids, eweights,
                                                         row_start, rank, edata, E, geb,
                                                         struc, deltab, Wall, bs, bv,
                                                         dstrb, kvb, N, nt, ndv);

    gemm_qk_kernel<<<dim3(384, 2), 256, 0, stream>>>(dstrb, Wall, bq, bk,
                                                     qb, kvb, N, nt);

    // edge attention + segment-sum
    aggregate_kernel<<<(N + 3) / 4, 256, 0, stream>>>(qb, kvb, row_start, edata, aggb, N);

    // out = in_feats + agg @ Wo^T
    gemm_out_kernel<<<nt, 256, 0, stream>>>(aggb, Wall + 4 * 16384, in_feats, out, N, nt);
}